// Round 11
// baseline (319.281 us; speedup 1.0000x reference)
//
#include <hip/hip_runtime.h>

// MemoryEfficientAttention: B=2,H=16,S=4096,D=128, CHUNK=1024.
// R11: dual q-stream waves. Each wave handles q-tiles 2t and 2t+1 (64 rows)
// sharing every K/V fragment load (1 ds_read -> 2 MFMA), doubling MFMA per
// barrier and giving 2 independent acc chains for latency hiding.
// nt(2t)==nt(2t+1)==t+1 -> zero divergence. Heavy-first dispatch pairs
// t=15-v with t=v per CU (sum 17). 64KB LDS (K,V dbuf), 1 barrier/tile,
// no-max softmax, pre-swizzled bf16 ws, gll16 DMA.

typedef __attribute__((ext_vector_type(8))) short bfrag_t;   // 8 bf16
typedef __attribute__((ext_vector_type(16))) float f32x16;
typedef unsigned short u16;
typedef unsigned int   u32;

#define SEQ     4096
#define SCHUNK  1024
#define HD      128
#define NTILE   16
#define TILE_E  8192

__device__ __forceinline__ u16 f2bf(float f) {
    union { float f; unsigned u; } x; x.f = f;
    unsigned r = x.u + 0x7fffu + ((x.u >> 16) & 1u);   // RNE
    return (u16)(r >> 16);
}

// ---------------- prep: f32 -> bf16, transpose V, bake LDS swizzle ----------------
// K tile: elem K[j][s*8+e] at j*128 + ((s ^ (j&15))*8) + e          (s=0..15)
// V^T tile: elem V[jo*8+jj][d] at d2*128 + (((jo + 8*(d&1)) ^ (d2&15))*8) + jj, d2=d>>1
__global__ __launch_bounds__(256)
void mea_prep(const float* __restrict__ kg, const float* __restrict__ vg,
              u16* __restrict__ wsK, u16* __restrict__ wsV)
{
    const int tid  = threadIdx.x;
    const int tile = blockIdx.x;            // 512 = 32 bh x 16 kt
    const int bh = tile >> 4, kt = tile & 15;
    const long gsrc = (long)bh * SEQ * HD + (long)kt * 64 * HD;
    const long gdst = (long)tile * TILE_E;

#pragma unroll
    for (int i = 0; i < 4; ++i) {
        int oid = i * 256 + tid;
        int j = oid >> 4, s = oid & 15;
        const float* kp = kg + gsrc + j * HD + s * 8;
        float4 a = *(const float4*)kp;
        float4 b = *(const float4*)(kp + 4);
        bfrag_t f;
        f[0]=f2bf(a.x); f[1]=f2bf(a.y); f[2]=f2bf(a.z); f[3]=f2bf(a.w);
        f[4]=f2bf(b.x); f[5]=f2bf(b.y); f[6]=f2bf(b.z); f[7]=f2bf(b.w);
        *(bfrag_t*)(wsK + gdst + j * 128 + ((s ^ (j & 15)) * 8)) = f;
    }
#pragma unroll
    for (int i = 0; i < 4; ++i) {
        int oid = i * 256 + tid;
        int jo = oid >> 7, d = oid & 127;
        const float* vp = vg + gsrc + jo * 8 * HD + d;
        bfrag_t f;
#pragma unroll
        for (int jj = 0; jj < 8; ++jj) f[jj] = f2bf(vp[jj * HD]);
        int d2 = d >> 1;
        int S  = (jo + ((d & 1) << 3)) ^ (d2 & 15);
        *(bfrag_t*)(wsV + gdst + d2 * 128 + S * 8) = f;
    }
}

__device__ __forceinline__ void gll16(const u16* g, u16* l) {
    __builtin_amdgcn_global_load_lds((const __attribute__((address_space(1))) u32*)g,
                                     (__attribute__((address_space(3))) u32*)l, 16, 0, 0);
}

__device__ __forceinline__ float tsum16(const f32x16& p) {
    float a0 = (p[0] + p[1]) + (p[2] + p[3]);
    float a1 = (p[4] + p[5]) + (p[6] + p[7]);
    float a2 = (p[8] + p[9]) + (p[10] + p[11]);
    float a3 = (p[12] + p[13]) + (p[14] + p[15]);
    return (a0 + a1) + (a2 + a3);
}

// exp2 in place, accumulate row-sum, pack to two PV A-fragments
__device__ __forceinline__ void sm_cvt(f32x16& s, float& lsum, bfrag_t* pf) {
#pragma unroll
    for (int r = 0; r < 16; ++r) s[r] = exp2f(s[r]);
    lsum += tsum16(s);
    u32 W[8];
#pragma unroll
    for (int t2 = 0; t2 < 8; ++t2)
        asm("v_cvt_pk_bf16_f32 %0, %1, %2"
            : "=v"(W[t2]) : "v"(s[2 * t2]), "v"(s[2 * t2 + 1]));
#pragma unroll
    for (int u2 = 0; u2 < 2; ++u2) {
        u32 x0 = W[4 * u2 + 0], y0 = W[4 * u2 + 2];
        u32 x1 = W[4 * u2 + 1], y1 = W[4 * u2 + 3];
        asm("v_permlane32_swap_b32 %0, %1" : "+v"(x0), "+v"(y0));
        asm("v_permlane32_swap_b32 %0, %1" : "+v"(x1), "+v"(y1));
        union { u32 w[4]; bfrag_t f; } cvt;
        cvt.w[0] = x0; cvt.w[1] = x1; cvt.w[2] = y0; cvt.w[3] = y1;
        pf[u2] = cvt.f;
    }
}

// ---------------- main attention kernel ----------------
__global__ __launch_bounds__(256, 2)
void mea_main(const float* __restrict__ qg, const u16* __restrict__ wsK,
              const u16* __restrict__ wsV, float* __restrict__ og)
{
    __shared__ __align__(16) u16 K_s[2][TILE_E];   // 16KB x2
    __shared__ __align__(16) u16 V_s[2][TILE_E];   // 16KB x2

    const int tid  = threadIdx.x;
    const int lane = tid & 63;
    const int wv   = tid >> 6;       // chunk 0..3
    const int c31  = lane & 31;
    const int hi   = lane >> 5;

    // XCD-aware; heavy (t=15..8) blocks dispatch first, light (t=0..7) second,
    // so round-robin pairs t and 15-t on each CU (sum 17 units).
    const int x    = blockIdx.x & 7;
    const int idx  = blockIdx.x >> 3;         // 0..63
    const int bh   = x * 4 + (idx & 3);
    const int half = idx >> 5;                // 0: heavy, 1: light
    const int v    = (idx & 31) >> 2;         // 0..7
    const int t    = half ? v : (15 - v);     // q-pair index: q-tiles 2t, 2t+1

    const long base = (long)bh * SEQ + (long)wv * SCHUNK + (long)t * 64;
    const u16* Kb = wsK + (long)bh * NTILE * TILE_E;
    const u16* Vb = wsV + (long)bh * NTILE * TILE_E;
    const int so   = wv * 2048 + lane * 8;
    const int ldsb = wv * 2048;
    const float qs = 0.12751723f;             // rsqrt(128) * log2(e)

    // ---- Q fragments, both streams (A: rows +c31, B: rows +32+c31)
    bfrag_t qfA[8], qfB[8];
#pragma unroll
    for (int st = 0; st < 2; ++st) {
        const float* qp = qg + (base + st * 32 + c31) * HD + hi * 8;
#pragma unroll
        for (int ks = 0; ks < 8; ++ks) {
            float4 a = *(const float4*)(qp + ks * 16);
            float4 b = *(const float4*)(qp + ks * 16 + 4);
            bfrag_t f;
            f[0]=f2bf(a.x*qs); f[1]=f2bf(a.y*qs); f[2]=f2bf(a.z*qs); f[3]=f2bf(a.w*qs);
            f[4]=f2bf(b.x*qs); f[5]=f2bf(b.y*qs); f[6]=f2bf(b.z*qs); f[7]=f2bf(b.w*qs);
            if (st == 0) qfA[ks] = f; else qfB[ks] = f;
        }
    }

    f32x16 oaccA[4], oaccB[4];
#pragma unroll
    for (int d = 0; d < 4; ++d)
#pragma unroll
        for (int i = 0; i < 16; ++i) { oaccA[d][i] = 0.f; oaccB[d][i] = 0.f; }
    float lsumA = 0.f, lsumB = 0.f;

    const int nt = t + 1;

    // prologue: DMA K(0), V(0) -> buf0
#pragma unroll
    for (int c = 0; c < 4; ++c) {
        gll16(Kb + so + c * 512, &K_s[0][ldsb + c * 512]);
        gll16(Vb + so + c * 512, &V_s[0][ldsb + c * 512]);
    }

    int cur = 0;
    for (int kt = 0; kt < nt; ++kt) {
        __syncthreads();   // K(kt),V(kt) landed everywhere; bufs ^1 free

        if (kt + 1 < nt) {
            const long tb = (long)(kt + 1) * TILE_E;
#pragma unroll
            for (int c = 0; c < 4; ++c) {
                gll16(Kb + tb + so + c * 512, &K_s[cur ^ 1][ldsb + c * 512]);
                gll16(Vb + tb + so + c * 512, &V_s[cur ^ 1][ldsb + c * 512]);
            }
        }

        const bool diag = (kt == nt - 1);
        bfrag_t pfA[2], pfB[2];

        // ======== g0: K rows 0..31, shared kf -> both streams ========
        {
            f32x16 sA, sB;
#pragma unroll
            for (int i = 0; i < 16; ++i) { sA[i] = 0.f; sB[i] = 0.f; }
            const u16* krow = &K_s[cur][c31 * 128];
#pragma unroll
            for (int ks = 0; ks < 8; ++ks) {
                int slot = (ks * 2 + hi) ^ (c31 & 15);
                bfrag_t kf = *(const bfrag_t*)(krow + slot * 8);
                sA = __builtin_amdgcn_mfma_f32_32x32x16_bf16(kf, qfA[ks], sA, 0, 0, 0);
                sB = __builtin_amdgcn_mfma_f32_32x32x16_bf16(kf, qfB[ks], sB, 0, 0, 0);
            }
            if (diag) {   // stream A diag: tri-mask g0 (B's g0 is fully visible)
#pragma unroll
                for (int r = 0; r < 16; ++r) {
                    int crow = (r & 3) + 8 * (r >> 2) + 4 * hi;
                    if (crow > c31) sA[r] = -1e30f;
                }
            }
            sm_cvt(sA, lsumA, pfA);
            sm_cvt(sB, lsumB, pfB);
        }
        // ---- PV jsl 0,1 (V rows 0..31), shared vf -> both streams
#pragma unroll
        for (int dg = 0; dg < 4; ++dg) {
            const int d  = dg * 32 + c31;
            const int d2 = d >> 1;
            const u16* vrow = &V_s[cur][d2 * 128];
#pragma unroll
            for (int jsl = 0; jsl < 2; ++jsl) {
                int S = ((jsl * 2 + hi) + ((d & 1) << 3)) ^ (d2 & 15);
                bfrag_t vf = *(const bfrag_t*)(vrow + S * 8);
                oaccA[dg] = __builtin_amdgcn_mfma_f32_32x32x16_bf16(vf, pfA[jsl], oaccA[dg], 0, 0, 0);
                oaccB[dg] = __builtin_amdgcn_mfma_f32_32x32x16_bf16(vf, pfB[jsl], oaccB[dg], 0, 0, 0);
            }
        }

        // ======== g1: K rows 32..63 ========
        if (!diag) {   // both streams full
            f32x16 sA, sB;
#pragma unroll
            for (int i = 0; i < 16; ++i) { sA[i] = 0.f; sB[i] = 0.f; }
            const u16* krow = &K_s[cur][(32 + c31) * 128];
#pragma unroll
            for (int ks = 0; ks < 8; ++ks) {
                int slot = (ks * 2 + hi) ^ (c31 & 15);
                bfrag_t kf = *(const bfrag_t*)(krow + slot * 8);
                sA = __builtin_amdgcn_mfma_f32_32x32x16_bf16(kf, qfA[ks], sA, 0, 0, 0);
                sB = __builtin_amdgcn_mfma_f32_32x32x16_bf16(kf, qfB[ks], sB, 0, 0, 0);
            }
            sm_cvt(sA, lsumA, pfA);
            sm_cvt(sB, lsumB, pfB);
#pragma unroll
            for (int dg = 0; dg < 4; ++dg) {
                const int d  = dg * 32 + c31;
                const int d2 = d >> 1;
                const u16* vrow = &V_s[cur][d2 * 128];
#pragma unroll
                for (int jsl = 0; jsl < 2; ++jsl) {
                    int S = ((jsl + 2) * 2 + hi + ((d & 1) << 3)) ^ (d2 & 15);
                    bfrag_t vf = *(const bfrag_t*)(vrow + S * 8);
                    oaccA[dg] = __builtin_amdgcn_mfma_f32_32x32x16_bf16(vf, pfA[jsl], oaccA[dg], 0, 0, 0);
                    oaccB[dg] = __builtin_amdgcn_mfma_f32_32x32x16_bf16(vf, pfB[jsl], oaccB[dg], 0, 0, 0);
                }
            }
        } else {       // diag: stream A's g1 fully masked -> B only, tri-masked
            f32x16 sB;
#pragma unroll
            for (int i = 0; i < 16; ++i) sB[i] = 0.f;
            const u16* krow = &K_s[cur][(32 + c31) * 128];
#pragma unroll
            for (int ks = 0; ks < 8; ++ks) {
                int slot = (ks * 2 + hi) ^ (c31 & 15);
                bfrag_t kf = *(const bfrag_t*)(krow + slot * 8);
                sB = __builtin_amdgcn_mfma_f32_32x32x16_bf16(kf, qfB[ks], sB, 0, 0, 0);
            }
#pragma unroll
            for (int r = 0; r < 16; ++r) {
                int crow = (r & 3) + 8 * (r >> 2) + 4 * hi;
                if (crow > c31) sB[r] = -1e30f;
            }
            sm_cvt(sB, lsumB, pfB);
#pragma unroll
            for (int dg = 0; dg < 4; ++dg) {
                const int d  = dg * 32 + c31;
                const int d2 = d >> 1;
                const u16* vrow = &V_s[cur][d2 * 128];
#pragma unroll
                for (int jsl = 0; jsl < 2; ++jsl) {
                    int S = ((jsl + 2) * 2 + hi + ((d & 1) << 3)) ^ (d2 & 15);
                    bfrag_t vf = *(const bfrag_t*)(vrow + S * 8);
                    oaccB[dg] = __builtin_amdgcn_mfma_f32_32x32x16_bf16(vf, pfB[jsl], oaccB[dg], 0, 0, 0);
                }
            }
        }

        cur ^= 1;
    }

    // ---- epilogue: per-stream cross-half lsum, divide, store
    lsumA += __shfl_xor(lsumA, 32);
    lsumB += __shfl_xor(lsumB, 32);
    float invA = 1.f / lsumA;
    float invB = 1.f / lsumB;
#pragma unroll
    for (int dg = 0; dg < 4; ++dg) {
#pragma unroll
        for (int rq = 0; rq < 4; ++rq) {
            float4 va, vb;
            va.x = oaccA[dg][rq * 4 + 0] * invA;
            va.y = oaccA[dg][rq * 4 + 1] * invA;
            va.z = oaccA[dg][rq * 4 + 2] * invA;
            va.w = oaccA[dg][rq * 4 + 3] * invA;
            vb.x = oaccB[dg][rq * 4 + 0] * invB;
            vb.y = oaccB[dg][rq * 4 + 1] * invB;
            vb.z = oaccB[dg][rq * 4 + 2] * invB;
            vb.w = oaccB[dg][rq * 4 + 3] * invB;
            *(float4*)(og + (base + c31) * HD      + dg * 32 + rq * 8 + hi * 4) = va;
            *(float4*)(og + (base + 32 + c31) * HD + dg * 32 + rq * 8 + hi * 4) = vb;
        }
    }
}

extern "C" void kernel_launch(void* const* d_in, const int* in_sizes, int n_in,
                              void* d_out, int out_size, void* d_ws, size_t ws_size,
                              hipStream_t stream)
{
    (void)in_sizes; (void)n_in; (void)out_size; (void)ws_size;
    const float* q = (const float*)d_in[0];
    const float* k = (const float*)d_in[1];
    const float* v = (const float*)d_in[2];
    float* o = (float*)d_out;
    u16* wsK = (u16*)d_ws;
    u16* wsV = wsK + (size_t)32 * NTILE * TILE_E;   // 8MB each
    mea_prep<<<dim3(512), dim3(256), 0, stream>>>(k, v, wsK, wsV);
    // grid: 512 blocks (2/CU), heavy t first; each wave = 64 q-rows (2 streams)
    mea_main<<<dim3(512), dim3(256), 0, stream>>>(q, wsK, wsV, o);
}

// Round 12
// 75.846 us; speedup vs baseline: 4.2096x; 4.2096x over previous
//
#include <hip/hip_runtime.h>

// MemoryEfficientAttention: B=2,H=16,S=4096,D=128, CHUNK=1024.
// R12: 8-wave blocks (512 thr), wave = (chunk c, q-half h): q-rows
// qt*64 + h*32. Each staged K/V tile serves 256 q-rows (2x R10) -> half
// the staging traffic. 256 blocks = exactly 1/CU; complement-paired
// segments qt=15-p then p => 17 K-tiles per block (perfect balance).
// Diagonal: h=0 tri-masks g0, skips g1; h=1 full g0, tri-masks g1.
// 64KB LDS (K,V dbuf), 1 barrier/tile, no-max softmax, pre-swizzled ws,
// gll16 DMA, setprio around MFMA clusters.

typedef __attribute__((ext_vector_type(8))) short bfrag_t;   // 8 bf16
typedef __attribute__((ext_vector_type(16))) float f32x16;
typedef unsigned short u16;
typedef unsigned int   u32;

#define SEQ     4096
#define SCHUNK  1024
#define HD      128
#define NTILE   16
#define TILE_E  8192

__device__ __forceinline__ u16 f2bf(float f) {
    union { float f; unsigned u; } x; x.f = f;
    unsigned r = x.u + 0x7fffu + ((x.u >> 16) & 1u);   // RNE
    return (u16)(r >> 16);
}

// ---------------- prep: f32 -> bf16, transpose V, bake LDS swizzle ----------------
// K tile: elem K[j][s*8+e] at j*128 + ((s ^ (j&15))*8) + e          (s=0..15)
// V^T tile: elem V[jo*8+jj][d] at d2*128 + (((jo + 8*(d&1)) ^ (d2&15))*8) + jj, d2=d>>1
__global__ __launch_bounds__(256)
void mea_prep(const float* __restrict__ kg, const float* __restrict__ vg,
              u16* __restrict__ wsK, u16* __restrict__ wsV)
{
    const int tid  = threadIdx.x;
    const int tile = blockIdx.x;            // 512 = 32 bh x 16 kt
    const int bh = tile >> 4, kt = tile & 15;
    const long gsrc = (long)bh * SEQ * HD + (long)kt * 64 * HD;
    const long gdst = (long)tile * TILE_E;

#pragma unroll
    for (int i = 0; i < 4; ++i) {
        int oid = i * 256 + tid;
        int j = oid >> 4, s = oid & 15;
        const float* kp = kg + gsrc + j * HD + s * 8;
        float4 a = *(const float4*)kp;
        float4 b = *(const float4*)(kp + 4);
        bfrag_t f;
        f[0]=f2bf(a.x); f[1]=f2bf(a.y); f[2]=f2bf(a.z); f[3]=f2bf(a.w);
        f[4]=f2bf(b.x); f[5]=f2bf(b.y); f[6]=f2bf(b.z); f[7]=f2bf(b.w);
        *(bfrag_t*)(wsK + gdst + j * 128 + ((s ^ (j & 15)) * 8)) = f;
    }
#pragma unroll
    for (int i = 0; i < 4; ++i) {
        int oid = i * 256 + tid;
        int jo = oid >> 7, d = oid & 127;
        const float* vp = vg + gsrc + jo * 8 * HD + d;
        bfrag_t f;
#pragma unroll
        for (int jj = 0; jj < 8; ++jj) f[jj] = f2bf(vp[jj * HD]);
        int d2 = d >> 1;
        int S  = (jo + ((d & 1) << 3)) ^ (d2 & 15);
        *(bfrag_t*)(wsV + gdst + d2 * 128 + S * 8) = f;
    }
}

__device__ __forceinline__ void gll16(const u16* g, u16* l) {
    __builtin_amdgcn_global_load_lds((const __attribute__((address_space(1))) u32*)g,
                                     (__attribute__((address_space(3))) u32*)l, 16, 0, 0);
}

__device__ __forceinline__ float tsum16(const f32x16& p) {
    float a0 = (p[0] + p[1]) + (p[2] + p[3]);
    float a1 = (p[4] + p[5]) + (p[6] + p[7]);
    float a2 = (p[8] + p[9]) + (p[10] + p[11]);
    float a3 = (p[12] + p[13]) + (p[14] + p[15]);
    return (a0 + a1) + (a2 + a3);
}

// exp2 in place, accumulate row-sum, pack to two PV A-fragments
__device__ __forceinline__ void sm_cvt(f32x16& s, float& lsum, bfrag_t* pf) {
#pragma unroll
    for (int r = 0; r < 16; ++r) s[r] = exp2f(s[r]);
    lsum += tsum16(s);
    u32 W[8];
#pragma unroll
    for (int t2 = 0; t2 < 8; ++t2)
        asm("v_cvt_pk_bf16_f32 %0, %1, %2"
            : "=v"(W[t2]) : "v"(s[2 * t2]), "v"(s[2 * t2 + 1]));
#pragma unroll
    for (int u2 = 0; u2 < 2; ++u2) {
        u32 x0 = W[4 * u2 + 0], y0 = W[4 * u2 + 2];
        u32 x1 = W[4 * u2 + 1], y1 = W[4 * u2 + 3];
        asm("v_permlane32_swap_b32 %0, %1" : "+v"(x0), "+v"(y0));
        asm("v_permlane32_swap_b32 %0, %1" : "+v"(x1), "+v"(y1));
        union { u32 w[4]; bfrag_t f; } cvt;
        cvt.w[0] = x0; cvt.w[1] = x1; cvt.w[2] = y0; cvt.w[3] = y1;
        pf[u2] = cvt.f;
    }
}

// ---------------- main attention kernel ----------------
__global__ __launch_bounds__(512, 2)
void mea_main(const float* __restrict__ qg, const u16* __restrict__ wsK,
              const u16* __restrict__ wsV, float* __restrict__ og)
{
    __shared__ __align__(16) u16 K_s[2][TILE_E];   // 16KB x2
    __shared__ __align__(16) u16 V_s[2][TILE_E];   // 16KB x2

    const int tid  = threadIdx.x;
    const int lane = tid & 63;
    const int wv   = tid >> 6;       // 0..7: chunk = wv&3, q-half h = wv>>2
    const int c31  = lane & 31;
    const int hi   = lane >> 5;
    const int ch   = wv & 3;
    const int h    = wv >> 2;

    // XCD-aware: 4 bh per XCD; 8 segment-pairs p per bh. 256 blocks = 1/CU.
    const int x   = blockIdx.x & 7;
    const int idx = blockIdx.x >> 3;          // 0..31
    const int bh  = x * 4 + (idx & 3);
    const int p   = idx >> 2;                 // 0..7

    const long bhrow = (long)bh * SEQ + (long)ch * SCHUNK + (long)h * 32;
    const u16* Kb = wsK + (long)bh * NTILE * TILE_E;
    const u16* Vb = wsV + (long)bh * NTILE * TILE_E;
    const int so   = wv * 1024 + lane * 8;    // wave's 2KB slice of each tile
    const int ldsb = wv * 1024;               // wave-uniform LDS dest base
    const float qs = 0.12751723f;             // rsqrt(128) * log2(e)

    // prologue: DMA K(0), V(0) of segment A -> buf0 (2+2 gll16 per wave)
#pragma unroll
    for (int c = 0; c < 2; ++c) {
        gll16(Kb + so + c * 512, &K_s[0][ldsb + c * 512]);
        gll16(Vb + so + c * 512, &V_s[0][ldsb + c * 512]);
    }

    int cur = 0;
    for (int seg = 0; seg < 2; ++seg) {
        const int qt = seg ? p : (15 - p);    // 64-row q-tile index
        const int nt = qt + 1;                // K-tile count (same for h=0,1)
        const long rowbase = bhrow + (long)qt * 64;   // this wave's first q-row

        // ---- Q fragments (B-op: n=q=c31, k=d=ks*16+hi*8+e); fold scale*log2e
        bfrag_t qf[8];
        {
            const float* qp = qg + (rowbase + c31) * HD + hi * 8;
#pragma unroll
            for (int ks = 0; ks < 8; ++ks) {
                float4 a = *(const float4*)(qp + ks * 16);
                float4 b = *(const float4*)(qp + ks * 16 + 4);
                bfrag_t f;
                f[0]=f2bf(a.x*qs); f[1]=f2bf(a.y*qs); f[2]=f2bf(a.z*qs); f[3]=f2bf(a.w*qs);
                f[4]=f2bf(b.x*qs); f[5]=f2bf(b.y*qs); f[6]=f2bf(b.z*qs); f[7]=f2bf(b.w*qs);
                qf[ks] = f;
            }
        }

        f32x16 oacc[4];
#pragma unroll
        for (int d = 0; d < 4; ++d)
#pragma unroll
            for (int i = 0; i < 16; ++i) oacc[d][i] = 0.f;
        float lsum = 0.f;

        for (int kt = 0; kt < nt; ++kt) {
            __syncthreads();   // vmcnt(0): K(kt),V(kt) landed everywhere; bufs ^1 free

            // prefetch next tile of this segment, or segment B's tile 0 at the seam
            if (kt + 1 < nt) {
                const long tb = (long)(kt + 1) * TILE_E;
#pragma unroll
                for (int c = 0; c < 2; ++c) {
                    gll16(Kb + tb + so + c * 512, &K_s[cur ^ 1][ldsb + c * 512]);
                    gll16(Vb + tb + so + c * 512, &V_s[cur ^ 1][ldsb + c * 512]);
                }
            } else if (seg == 0) {
#pragma unroll
                for (int c = 0; c < 2; ++c) {
                    gll16(Kb + so + c * 512, &K_s[cur ^ 1][ldsb + c * 512]);
                    gll16(Vb + so + c * 512, &V_s[cur ^ 1][ldsb + c * 512]);
                }
            }

            const bool diag = (kt == nt - 1);
            const bool do1  = !(diag && h == 0);   // h=0 diagonal: g1 fully masked
            bfrag_t pfA[2], pfB[2];

            // ======== g0: K rows 0..31 ========
            {
                f32x16 s;
#pragma unroll
                for (int i = 0; i < 16; ++i) s[i] = 0.f;
                const u16* krow = &K_s[cur][c31 * 128];
                __builtin_amdgcn_s_setprio(1);
#pragma unroll
                for (int ks = 0; ks < 8; ++ks) {
                    int slot = (ks * 2 + hi) ^ (c31 & 15);
                    bfrag_t kf = *(const bfrag_t*)(krow + slot * 8);
                    s = __builtin_amdgcn_mfma_f32_32x32x16_bf16(kf, qf[ks], s, 0, 0, 0);
                }
                __builtin_amdgcn_s_setprio(0);
                if (diag && h == 0) {   // tri-mask: k-row > q-row
#pragma unroll
                    for (int r = 0; r < 16; ++r) {
                        int crow = (r & 3) + 8 * (r >> 2) + 4 * hi;
                        if (crow > c31) s[r] = -1e30f;
                    }
                }
                sm_cvt(s, lsum, pfA);
            }
            // ======== g1: K rows 32..63 ========
            if (do1) {
                f32x16 s;
#pragma unroll
                for (int i = 0; i < 16; ++i) s[i] = 0.f;
                const u16* krow = &K_s[cur][(32 + c31) * 128];
                __builtin_amdgcn_s_setprio(1);
#pragma unroll
                for (int ks = 0; ks < 8; ++ks) {
                    int slot = (ks * 2 + hi) ^ (c31 & 15);
                    bfrag_t kf = *(const bfrag_t*)(krow + slot * 8);
                    s = __builtin_amdgcn_mfma_f32_32x32x16_bf16(kf, qf[ks], s, 0, 0, 0);
                }
                __builtin_amdgcn_s_setprio(0);
                if (diag) {             // h=1 diagonal: tri-mask g1
#pragma unroll
                    for (int r = 0; r < 16; ++r) {
                        int crow = (r & 3) + 8 * (r >> 2) + 4 * hi;
                        if (crow > c31) s[r] = -1e30f;
                    }
                }
                sm_cvt(s, lsum, pfB);
            }

            // ---- O^T += V^T * P^T (V[cur] stable: prefetch went to [cur^1])
            __builtin_amdgcn_s_setprio(1);
#pragma unroll
            for (int dg = 0; dg < 4; ++dg) {
                const int d  = dg * 32 + c31;
                const int d2 = d >> 1;
                const u16* vrow = &V_s[cur][d2 * 128];
#pragma unroll
                for (int jsl = 0; jsl < 2; ++jsl) {
                    int S = ((jsl * 2 + hi) + ((d & 1) << 3)) ^ (d2 & 15);
                    bfrag_t vf = *(const bfrag_t*)(vrow + S * 8);
                    oacc[dg] = __builtin_amdgcn_mfma_f32_32x32x16_bf16(vf, pfA[jsl], oacc[dg], 0, 0, 0);
                }
                if (do1) {
#pragma unroll
                    for (int jsl = 0; jsl < 2; ++jsl) {
                        int S = ((jsl + 2) * 2 + hi + ((d & 1) << 3)) ^ (d2 & 15);
                        bfrag_t vf = *(const bfrag_t*)(vrow + S * 8);
                        oacc[dg] = __builtin_amdgcn_mfma_f32_32x32x16_bf16(vf, pfB[jsl], oacc[dg], 0, 0, 0);
                    }
                }
            }
            __builtin_amdgcn_s_setprio(0);

            cur ^= 1;
        }

        // ---- per-segment epilogue: cross-half lsum, divide, store
        lsum += __shfl_xor(lsum, 32);
        float inv = 1.f / lsum;
#pragma unroll
        for (int dg = 0; dg < 4; ++dg) {
#pragma unroll
            for (int rq = 0; rq < 4; ++rq) {
                float4 v;
                v.x = oacc[dg][rq * 4 + 0] * inv;
                v.y = oacc[dg][rq * 4 + 1] * inv;
                v.z = oacc[dg][rq * 4 + 2] * inv;
                v.w = oacc[dg][rq * 4 + 3] * inv;
                *(float4*)(og + (rowbase + c31) * HD + dg * 32 + rq * 8 + hi * 4) = v;
            }
        }
    }
}

extern "C" void kernel_launch(void* const* d_in, const int* in_sizes, int n_in,
                              void* d_out, int out_size, void* d_ws, size_t ws_size,
                              hipStream_t stream)
{
    (void)in_sizes; (void)n_in; (void)out_size; (void)ws_size;
    const float* q = (const float*)d_in[0];
    const float* k = (const float*)d_in[1];
    const float* v = (const float*)d_in[2];
    float* o = (float*)d_out;
    u16* wsK = (u16*)d_ws;
    u16* wsV = wsK + (size_t)32 * NTILE * TILE_E;   // 8MB each
    mea_prep<<<dim3(512), dim3(256), 0, stream>>>(k, v, wsK, wsV);
    // grid: 256 blocks x 512 thr = exactly 1 block/CU; 17 K-tiles per block
    mea_main<<<dim3(256), dim3(512), 0, stream>>>(q, wsK, wsV, o);
}